// Round 2
// baseline (3748.923 us; speedup 1.0000x reference)
//
#include <hip/hip_runtime.h>
#include <hip/hip_cooperative_groups.h>
#include <math.h>

namespace cg = cooperative_groups;

#define NS 16
#define NITERS 40
#define TPB 256
#define CG_TPB 1024
#define CG_BLOCKS 256

__device__ __forceinline__ float4 ld4(const float* p) {
    return *reinterpret_cast<const float4*>(p);
}
__device__ __forceinline__ void st4(float* p, float4 v) {
    *reinterpret_cast<float4*>(p) = v;
}

// ---------------------------------------------------------------------------
// COO -> stencil scatter (unchanged from round 1; validated).
// ---------------------------------------------------------------------------
__global__ __launch_bounds__(TPB) void k_scatter(
    const int* __restrict__ row, const int* __restrict__ col,
    const float* __restrict__ val, float* __restrict__ W,
    float* __restrict__ diagL, int nnz, int nV, int stride) {
    int e = blockIdx.x * TPB + threadIdx.x;
    if (e >= nnz) return;
    int r = row[e], c = col[e];
    float v = val[e];
    if (r == c) { atomicAdd(&diagL[r], v); return; }
    int off = c - r;
    int slot;
    if      (off == -stride - 1) slot = 0;
    else if (off == -stride)     slot = 1;
    else if (off == -1)          slot = 2;
    else if (off == 1)           slot = 3;
    else if (off == stride)      slot = 4;
    else if (off == stride + 1)  slot = 5;
    else return;
    atomicAdd(&W[slot * nV + r], v);
}

__global__ __launch_bounds__(TPB) void k_diag(
    const float* __restrict__ M_diag, const float* __restrict__ diagL,
    const float* __restrict__ tptr, float* __restrict__ Adiag,
    float* __restrict__ Minv, int nV) {
    int v = blockIdx.x * TPB + threadIdx.x;
    if (v >= nV) return;
    float t = tptr[0];
    float a = M_diag[v] + t * diagL[v];
    Adiag[v] = a;
    Minv[v] = 1.0f / fmaxf(a, 1e-12f);
}

// ---------------------------------------------------------------------------
// Reduce per-thread float4 partials (seed classes (tid&3)*4..+3) to 16 sums,
// one atomicAdd per seed per block. Must be called by ALL threads of block.
// ---------------------------------------------------------------------------
__device__ __forceinline__ void reduce_accum_16(float4 val, float* dst,
                                                float4* sm) {
#pragma unroll
    for (int off = 4; off < 64; off <<= 1) {
        val.x += __shfl_xor(val.x, off, 64);
        val.y += __shfl_xor(val.y, off, 64);
        val.z += __shfl_xor(val.z, off, 64);
        val.w += __shfl_xor(val.w, off, 64);
    }
    const int tid = threadIdx.x, lane = tid & 63, wave = tid >> 6;
    if (lane < 4) sm[wave * 4 + lane] = val;
    __syncthreads();
    if (tid < 4) {
        float4 acc = sm[tid];
#pragma unroll
        for (int w2 = 1; w2 < CG_TPB / 64; ++w2) {
            float4 o = sm[w2 * 4 + tid];
            acc.x += o.x; acc.y += o.y; acc.z += o.z; acc.w += o.w;
        }
        atomicAdd(&dst[tid * 4 + 0], acc.x);
        atomicAdd(&dst[tid * 4 + 1], acc.y);
        atomicAdd(&dst[tid * 4 + 2], acc.z);
        atomicAdd(&dst[tid * 4 + 3], acc.w);
    }
    __syncthreads();  // protect sm reuse next call
}

struct CgArgs {
    const float* B;
    const float* W;
    const float* Adiag;
    const float* Minv;
    const float* tptr;
    float* P;
    float* dots;
    float* U;      // d_out
    float* S;      // d_out + ntot + nF*48
    float* Xdir;   // d_out + ntot
    const int* F;
    const float* gI;
    const float* gJ;
    const float* gK;
    int nV;
    int nF;
    int stride;
};

// ---------------------------------------------------------------------------
// Whole pipeline after scatter/diag: CG init + 40 iterations + S + Xdir.
// Thread t owns vertex v = t>>2, seeds sb..sb+3 (sb = (t&3)*4) => element
// block e = 4*t (one float4). X, R, AP live in registers; only P in memory.
// ---------------------------------------------------------------------------
__global__ __launch_bounds__(CG_TPB, 4) void k_cg(CgArgs a) {
    cg::grid_group grid = cg::this_grid();
    __shared__ float4 sm[(CG_TPB / 64) * 4];

    const int t   = blockIdx.x * CG_TPB + threadIdx.x;
    const int v   = t >> 2;
    const int sb  = (t & 3) * 4;
    const int e   = t * 4;
    const int nV  = a.nV;
    const bool active = (v < nV);

    // Per-vertex constants
    float w0 = 0, w1 = 0, w2 = 0, w3 = 0, w4 = 0, w5 = 0, ad = 0, mi = 0;
    int n0 = 0, n1 = 0, n2 = 0, n3 = 0, n4 = 0, n5 = 0;
    const float tt = a.tptr[0];
    if (active) {
        w0 = a.W[0 * nV + v]; w1 = a.W[1 * nV + v]; w2 = a.W[2 * nV + v];
        w3 = a.W[3 * nV + v]; w4 = a.W[4 * nV + v]; w5 = a.W[5 * nV + v];
        ad = a.Adiag[v]; mi = a.Minv[v];
        const int st = a.stride;
        n0 = max(0, min(v - st - 1, nV - 1)) * NS + sb;
        n1 = max(0, min(v - st,     nV - 1)) * NS + sb;
        n2 = max(0, min(v - 1,      nV - 1)) * NS + sb;
        n3 = max(0, min(v + 1,      nV - 1)) * NS + sb;
        n4 = max(0, min(v + st,     nV - 1)) * NS + sb;
        n5 = max(0, min(v + st + 1, nV - 1)) * NS + sb;
    }

    // ---- init: X=0, R=B, P=Z=Minv*R, rz0 -> dots[0:16]
    float4 x = make_float4(0, 0, 0, 0);
    float4 r = make_float4(0, 0, 0, 0);
    float4 p = make_float4(0, 0, 0, 0);
    float4 partial = make_float4(0, 0, 0, 0);
    if (active) {
        r = ld4(a.B + e);
        p = make_float4(mi * r.x, mi * r.y, mi * r.z, mi * r.w);
        st4(a.P + e, p);
        partial = make_float4(r.x * p.x, r.y * p.y, r.z * p.z, r.w * p.w);
    }
    reduce_accum_16(partial, a.dots, sm);
    grid.sync();

    float4 ap = make_float4(0, 0, 0, 0);
    for (int i = 0; i < NITERS; ++i) {
        // ---- stage A: AP = Adiag*P + t * sum W_k * P[nbr_k]; denom partial
        partial = make_float4(0, 0, 0, 0);
        if (active) {
            float4 q0 = ld4(a.P + n0), q1 = ld4(a.P + n1), q2 = ld4(a.P + n2);
            float4 q3 = ld4(a.P + n3), q4 = ld4(a.P + n4), q5 = ld4(a.P + n5);
            ap.x = ad * p.x + tt * (w0 * q0.x + w1 * q1.x + w2 * q2.x +
                                    w3 * q3.x + w4 * q4.x + w5 * q5.x);
            ap.y = ad * p.y + tt * (w0 * q0.y + w1 * q1.y + w2 * q2.y +
                                    w3 * q3.y + w4 * q4.y + w5 * q5.y);
            ap.z = ad * p.z + tt * (w0 * q0.z + w1 * q1.z + w2 * q2.z +
                                    w3 * q3.z + w4 * q4.z + w5 * q5.z);
            ap.w = ad * p.w + tt * (w0 * q0.w + w1 * q1.w + w2 * q2.w +
                                    w3 * q3.w + w4 * q4.w + w5 * q5.w);
            partial = make_float4(p.x * ap.x, p.y * ap.y, p.z * ap.z, p.w * ap.w);
        }
        reduce_accum_16(partial, a.dots + (2 * i + 1) * NS, sm);
        grid.sync();

        // ---- stage B: alpha; X += aP; R -= aAP; z = Minv*R; rz_new partial
        float4 rz = ld4(a.dots + (2 * i) * NS + sb);
        float4 dn = ld4(a.dots + (2 * i + 1) * NS + sb);
        float4 z = make_float4(0, 0, 0, 0);
        partial = make_float4(0, 0, 0, 0);
        if (active) {
            float ax = rz.x / fmaxf(dn.x, 1e-30f);
            float ay = rz.y / fmaxf(dn.y, 1e-30f);
            float az = rz.z / fmaxf(dn.z, 1e-30f);
            float aw = rz.w / fmaxf(dn.w, 1e-30f);
            x.x += ax * p.x; x.y += ay * p.y; x.z += az * p.z; x.w += aw * p.w;
            r.x -= ax * ap.x; r.y -= ay * ap.y; r.z -= az * ap.z; r.w -= aw * ap.w;
            z = make_float4(mi * r.x, mi * r.y, mi * r.z, mi * r.w);
            partial = make_float4(r.x * z.x, r.y * z.y, r.z * z.z, r.w * z.w);
        }
        if (i == NITERS - 1) {
            // Final: write U and S, no more P update needed.
            if (active) {
                st4(a.U + e, x);
                float4 s4;
                float u0 = x.x, u1 = x.y, u2 = x.z, u3 = x.w;
                u0 = isnan(u0) ? 1e-9f : (isinf(u0) ? (u0 > 0 ? 1.0f : 0.0f) : u0);
                u1 = isnan(u1) ? 1e-9f : (isinf(u1) ? (u1 > 0 ? 1.0f : 0.0f) : u1);
                u2 = isnan(u2) ? 1e-9f : (isinf(u2) ? (u2 > 0 ? 1.0f : 0.0f) : u2);
                u3 = isnan(u3) ? 1e-9f : (isinf(u3) ? (u3 > 0 ? 1.0f : 0.0f) : u3);
                s4.x = -logf(fmaxf(u0, 1e-9f));
                s4.y = -logf(fmaxf(u1, 1e-9f));
                s4.z = -logf(fmaxf(u2, 1e-9f));
                s4.w = -logf(fmaxf(u3, 1e-9f));
                st4(a.S + e, s4);
            }
            break;
        }
        reduce_accum_16(partial, a.dots + (2 * i + 2) * NS, sm);
        grid.sync();

        // ---- stage C: beta; P = z + beta*P; publish P
        float4 rzn = ld4(a.dots + (2 * i + 2) * NS + sb);
        if (active) {
            float bx = rzn.x / fmaxf(rz.x, 1e-30f);
            float by = rzn.y / fmaxf(rz.y, 1e-30f);
            float bz = rzn.z / fmaxf(rz.z, 1e-30f);
            float bw = rzn.w / fmaxf(rz.w, 1e-30f);
            p.x = z.x + bx * p.x; p.y = z.y + by * p.y;
            p.z = z.z + bz * p.z; p.w = z.w + bw * p.w;
            st4(a.P + e, p);
        }
        grid.sync();
    }

    grid.sync();  // U visible to everyone

    // ---- epilogue: Xdir per (face, seed-quad) chunk
    const int nchunks = a.nF * 4;
    const int gsz = gridDim.x * CG_TPB;
    for (int idx = t; idx < nchunks; idx += gsz) {
        int f = idx >> 2;
        int sb2 = (idx & 3) * 4;
        int i0 = a.F[3 * f + 0], i1 = a.F[3 * f + 1], i2 = a.F[3 * f + 2];
        float4 uI = ld4(a.U + i0 * NS + sb2);
        float4 uJ = ld4(a.U + i1 * NS + sb2);
        float4 uK = ld4(a.U + i2 * NS + sb2);
        float gIx = a.gI[3 * f], gIy = a.gI[3 * f + 1], gIz = a.gI[3 * f + 2];
        float gJx = a.gJ[3 * f], gJy = a.gJ[3 * f + 1], gJz = a.gJ[3 * f + 2];
        float gKx = a.gK[3 * f], gKy = a.gK[3 * f + 1], gKz = a.gK[3 * f + 2];
        float4 gx, gy, gz;
        gx.x = uI.x * gIx + uJ.x * gJx + uK.x * gKx;
        gx.y = uI.y * gIx + uJ.y * gJx + uK.y * gKx;
        gx.z = uI.z * gIx + uJ.z * gJx + uK.z * gKx;
        gx.w = uI.w * gIx + uJ.w * gJx + uK.w * gKx;
        gy.x = uI.x * gIy + uJ.x * gJy + uK.x * gKy;
        gy.y = uI.y * gIy + uJ.y * gJy + uK.y * gKy;
        gy.z = uI.z * gIy + uJ.z * gJy + uK.z * gKy;
        gy.w = uI.w * gIy + uJ.w * gJy + uK.w * gKy;
        gz.x = uI.x * gIz + uJ.x * gJz + uK.x * gKz;
        gz.y = uI.y * gIz + uJ.y * gJz + uK.y * gKz;
        gz.z = uI.z * gIz + uJ.z * gJz + uK.z * gKz;
        gz.w = uI.w * gIz + uJ.w * gJz + uK.w * gKz;
        float4 iv;
        iv.x = -1.0f / fmaxf(sqrtf(gx.x * gx.x + gy.x * gy.x + gz.x * gz.x), 1e-12f);
        iv.y = -1.0f / fmaxf(sqrtf(gx.y * gx.y + gy.y * gy.y + gz.y * gz.y), 1e-12f);
        iv.z = -1.0f / fmaxf(sqrtf(gx.z * gx.z + gy.z * gy.z + gz.z * gz.z), 1e-12f);
        iv.w = -1.0f / fmaxf(sqrtf(gx.w * gx.w + gy.w * gy.w + gz.w * gz.w), 1e-12f);
        float* o = a.Xdir + (size_t)f * 48 + sb2 * 3;
        st4(o + 0, make_float4(gx.x * iv.x, gy.x * iv.x, gz.x * iv.x, gx.y * iv.y));
        st4(o + 4, make_float4(gy.y * iv.y, gz.y * iv.y, gx.z * iv.z, gy.z * iv.z));
        st4(o + 8, make_float4(gz.z * iv.z, gx.w * iv.w, gy.w * iv.w, gz.w * iv.w));
    }
}

extern "C" void kernel_launch(void* const* d_in, const int* in_sizes, int n_in,
                              void* d_out, int out_size, void* d_ws, size_t ws_size,
                              hipStream_t stream) {
    const int*   F      = (const int*)d_in[0];
    const int*   row    = (const int*)d_in[1];
    const int*   col    = (const int*)d_in[2];
    const float* val    = (const float*)d_in[3];
    const float* M_diag = (const float*)d_in[4];
    const float* gI     = (const float*)d_in[5];
    const float* gJ     = (const float*)d_in[6];
    const float* gK     = (const float*)d_in[7];
    const float* B      = (const float*)d_in[8];
    const float* tptr   = (const float*)d_in[9];

    const int nF   = in_sizes[0] / 3;        // 130050
    const int nnz  = in_sizes[1];            // 1560600
    const int nV   = in_sizes[4];            // 65536
    const int ntot = nV * NS;                // 1048576
    const int stride = (int)(sqrt((double)nV) + 0.5);  // 256

    float* out = (float*)d_out;
    float* U = out;
    float* Xdir = out + (size_t)ntot;
    float* S = out + (size_t)ntot + (size_t)nF * 48;

    // Scratch inside the Xdir region (dead before epilogue overwrites it):
    float* P     = Xdir;                           // ntot
    float* W     = Xdir + (size_t)ntot;            // 6*nV
    float* diagL = W + (size_t)6 * nV;             // nV
    float* Adiag = diagL + nV;                     // nV
    float* Minv  = Adiag + nV;                     // nV
    float* dots  = Minv + nV;                      // (2*NITERS+2)*16

    hipMemsetAsync(W, 0, (size_t)7 * nV * sizeof(float), stream);
    hipMemsetAsync(dots, 0, (size_t)(2 * NITERS + 2) * NS * sizeof(float), stream);

    k_scatter<<<(nnz + TPB - 1) / TPB, TPB, 0, stream>>>(row, col, val, W, diagL,
                                                         nnz, nV, stride);
    k_diag<<<(nV + TPB - 1) / TPB, TPB, 0, stream>>>(M_diag, diagL, tptr,
                                                     Adiag, Minv, nV);

    CgArgs a;
    a.B = B; a.W = W; a.Adiag = Adiag; a.Minv = Minv; a.tptr = tptr;
    a.P = P; a.dots = dots; a.U = U; a.S = S; a.Xdir = Xdir;
    a.F = F; a.gI = gI; a.gJ = gJ; a.gK = gK;
    a.nV = nV; a.nF = nF; a.stride = stride;

    void* args[] = { &a };
    int blocks = (nV * 4 + CG_TPB - 1) / CG_TPB;   // 256 for nV=65536
    hipLaunchCooperativeKernel((void*)k_cg, dim3(blocks), dim3(CG_TPB),
                               args, 0, stream);
}

// Round 3
// 2151.295 us; speedup vs baseline: 1.7426x; 1.7426x over previous
//
#include <hip/hip_runtime.h>
#include <math.h>

#define NS 16
#define NITERS 40
#define TPB 256
#define CG_TPB 1024

__device__ __forceinline__ float4 ld4(const float* p) {
    return *reinterpret_cast<const float4*>(p);
}
__device__ __forceinline__ void st4(float* p, float4 v) {
    *reinterpret_cast<float4*>(p) = v;
}

// ---------------------------------------------------------------------------
// COO -> stencil scatter (validated round 1).
// ---------------------------------------------------------------------------
__global__ __launch_bounds__(TPB) void k_scatter(
    const int* __restrict__ row, const int* __restrict__ col,
    const float* __restrict__ val, float* __restrict__ W,
    float* __restrict__ diagL, int nnz, int nV, int stride) {
    int e = blockIdx.x * TPB + threadIdx.x;
    if (e >= nnz) return;
    int r = row[e], c = col[e];
    float v = val[e];
    if (r == c) { atomicAdd(&diagL[r], v); return; }
    int off = c - r;
    int slot;
    if      (off == -stride - 1) slot = 0;
    else if (off == -stride)     slot = 1;
    else if (off == -1)          slot = 2;
    else if (off == 1)           slot = 3;
    else if (off == stride)      slot = 4;
    else if (off == stride + 1)  slot = 5;
    else return;
    atomicAdd(&W[slot * nV + r], v);
}

__global__ __launch_bounds__(TPB) void k_diag(
    const float* __restrict__ M_diag, const float* __restrict__ diagL,
    const float* __restrict__ tptr, float* __restrict__ Adiag,
    float* __restrict__ Minv, int nV) {
    int v = blockIdx.x * TPB + threadIdx.x;
    if (v >= nV) return;
    float t = tptr[0];
    float a = M_diag[v] + t * diagL[v];
    Adiag[v] = a;
    Minv[v] = 1.0f / fmaxf(a, 1e-12f);
}

// ---------------------------------------------------------------------------
// Lightweight grid barrier: agent-scope counter, relaxed polling.
// All blocks must be co-resident (cooperative launch guarantees this).
// ---------------------------------------------------------------------------
__device__ __forceinline__ void gbar(int* cnt, int target) {
    __syncthreads();
    if (threadIdx.x == 0) {
        __threadfence();  // release: publish this block's prior writes
        __hip_atomic_fetch_add(cnt, 1, __ATOMIC_RELAXED,
                               __HIP_MEMORY_SCOPE_AGENT);
        while (__hip_atomic_load(cnt, __ATOMIC_RELAXED,
                                 __HIP_MEMORY_SCOPE_AGENT) < target) {
            __builtin_amdgcn_s_sleep(1);
        }
        __threadfence();  // acquire: invalidate stale cached data
    }
    __syncthreads();
}

// Reduce per-thread float4 partials (seed classes (tid&3)*4..+3) to 16 sums,
// one atomicAdd per seed per block. Validated round 2.
__device__ __forceinline__ void reduce_accum_16(float4 val, float* dst,
                                                float4* sm) {
#pragma unroll
    for (int off = 4; off < 64; off <<= 1) {
        val.x += __shfl_xor(val.x, off, 64);
        val.y += __shfl_xor(val.y, off, 64);
        val.z += __shfl_xor(val.z, off, 64);
        val.w += __shfl_xor(val.w, off, 64);
    }
    const int tid = threadIdx.x, lane = tid & 63, wave = tid >> 6;
    if (lane < 4) sm[wave * 4 + lane] = val;
    __syncthreads();
    if (tid < 4) {
        float4 acc = sm[tid];
#pragma unroll
        for (int w2 = 1; w2 < CG_TPB / 64; ++w2) {
            float4 o = sm[w2 * 4 + tid];
            acc.x += o.x; acc.y += o.y; acc.z += o.z; acc.w += o.w;
        }
        atomicAdd(&dst[tid * 4 + 0], acc.x);
        atomicAdd(&dst[tid * 4 + 1], acc.y);
        atomicAdd(&dst[tid * 4 + 2], acc.z);
        atomicAdd(&dst[tid * 4 + 3], acc.w);
    }
    __syncthreads();
}

struct CgArgs {
    const float* B;
    const float* W;
    const float* Adiag;
    const float* Minv;
    const float* tptr;
    float* Ubuf;   // u = Minv*r, the only memory-resident CG vector
    float* dots;   // gamma_i at slot 2i, delta_i at slot 2i+1 (16 floats each)
    int*   cnt;    // barrier counter
    float* U;      // d_out
    float* S;
    float* Xdir;
    const int* F;
    const float* gI;
    const float* gJ;
    const float* gK;
    int nV;
    int nF;
    int stride;
    int nblocks;
};

// ---------------------------------------------------------------------------
// Chronopoulos-Gear PCG (one matvec + one fused reduction pair per iter):
//   gamma_i=(r_i,u_i), delta_i=(w_i,u_i), w_i = A u_i
//   beta_i = gamma_i/gamma_{i-1} (0 at i=0)
//   alpha_i = gamma_i / (delta_i - beta_i*gamma_i/alpha_{i-1})
//   p=u+beta p; s=w+beta s; x+=alpha p; r-=alpha s; u=Minv r
// Exact-arithmetic identical to reference PCG; same 1e-30 guards.
// Thread t owns vertex v (XCD-banded), seeds sb..sb+3. x,r,p,s,w in regs.
// 2 barriers/iteration.
// ---------------------------------------------------------------------------
__global__ __launch_bounds__(CG_TPB, 4) void k_cg(CgArgs a) {
    __shared__ float4 sm[(CG_TPB / 64) * 4];
    const int nV = a.nV;
    const int nb = a.nblocks;

    // XCD-banded ownership: XCD (b%8) owns 32 contiguous grid rows.
    const int ob = (blockIdx.x % 8) * (nb / 8) + blockIdx.x / 8;
    const int t  = ob * CG_TPB + threadIdx.x;
    const int v  = t >> 2;
    const int sb = (t & 3) * 4;
    const int e  = t * 4;

    const float tt = a.tptr[0];
    const float w0 = a.W[0 * nV + v], w1 = a.W[1 * nV + v];
    const float w2 = a.W[2 * nV + v], w3 = a.W[3 * nV + v];
    const float w4 = a.W[4 * nV + v], w5 = a.W[5 * nV + v];
    const float ad = a.Adiag[v];
    const float mi = a.Minv[v];
    const int st = a.stride;
    const int n0 = max(0, min(v - st - 1, nV - 1)) * NS + sb;
    const int n1 = max(0, min(v - st,     nV - 1)) * NS + sb;
    const int n2 = max(0, min(v - 1,      nV - 1)) * NS + sb;
    const int n3 = max(0, min(v + 1,      nV - 1)) * NS + sb;
    const int n4 = max(0, min(v + st,     nV - 1)) * NS + sb;
    const int n5 = max(0, min(v + st + 1, nV - 1)) * NS + sb;

    int epoch = 0;

    // ---- init: r=B, u=Minv*r, gamma0=(r,u); x=p=s=0
    float4 x = make_float4(0, 0, 0, 0);
    float4 p = make_float4(0, 0, 0, 0);
    float4 s = make_float4(0, 0, 0, 0);
    float4 r = ld4(a.B + e);
    float4 u = make_float4(mi * r.x, mi * r.y, mi * r.z, mi * r.w);
    st4(a.Ubuf + e, u);
    reduce_accum_16(make_float4(r.x * u.x, r.y * u.y, r.z * u.z, r.w * u.w),
                    a.dots + 0, sm);
    gbar(a.cnt, (++epoch) * nb);

    // ---- w0 = A u0 ; delta0=(w,u)
    float4 w;
    {
        float4 q0 = ld4(a.Ubuf + n0), q1 = ld4(a.Ubuf + n1),
               q2 = ld4(a.Ubuf + n2), q3 = ld4(a.Ubuf + n3),
               q4 = ld4(a.Ubuf + n4), q5 = ld4(a.Ubuf + n5);
        w.x = ad * u.x + tt * (w0 * q0.x + w1 * q1.x + w2 * q2.x +
                               w3 * q3.x + w4 * q4.x + w5 * q5.x);
        w.y = ad * u.y + tt * (w0 * q0.y + w1 * q1.y + w2 * q2.y +
                               w3 * q3.y + w4 * q4.y + w5 * q5.y);
        w.z = ad * u.z + tt * (w0 * q0.z + w1 * q1.z + w2 * q2.z +
                               w3 * q3.z + w4 * q4.z + w5 * q5.z);
        w.w = ad * u.w + tt * (w0 * q0.w + w1 * q1.w + w2 * q2.w +
                               w3 * q3.w + w4 * q4.w + w5 * q5.w);
    }
    reduce_accum_16(make_float4(w.x * u.x, w.y * u.y, w.z * u.z, w.w * u.w),
                    a.dots + NS, sm);
    gbar(a.cnt, (++epoch) * nb);

    float4 gp = make_float4(1, 1, 1, 1);   // gamma_{i-1}
    float4 alp = make_float4(1, 1, 1, 1);  // alpha_{i-1}
    for (int i = 0; i < NITERS; ++i) {
        float4 g = ld4(a.dots + (2 * i) * NS + sb);
        float4 d = ld4(a.dots + (2 * i + 1) * NS + sb);
        float4 beta, alpha;
        if (i == 0) {
            beta = make_float4(0, 0, 0, 0);
            alpha.x = g.x / fmaxf(d.x, 1e-30f);
            alpha.y = g.y / fmaxf(d.y, 1e-30f);
            alpha.z = g.z / fmaxf(d.z, 1e-30f);
            alpha.w = g.w / fmaxf(d.w, 1e-30f);
        } else {
            beta.x = g.x / fmaxf(gp.x, 1e-30f);
            beta.y = g.y / fmaxf(gp.y, 1e-30f);
            beta.z = g.z / fmaxf(gp.z, 1e-30f);
            beta.w = g.w / fmaxf(gp.w, 1e-30f);
            alpha.x = g.x / fmaxf(d.x - beta.x * g.x / alp.x, 1e-30f);
            alpha.y = g.y / fmaxf(d.y - beta.y * g.y / alp.y, 1e-30f);
            alpha.z = g.z / fmaxf(d.z - beta.z * g.z / alp.z, 1e-30f);
            alpha.w = g.w / fmaxf(d.w - beta.w * g.w / alp.w, 1e-30f);
        }
        p.x = u.x + beta.x * p.x; p.y = u.y + beta.y * p.y;
        p.z = u.z + beta.z * p.z; p.w = u.w + beta.w * p.w;
        s.x = w.x + beta.x * s.x; s.y = w.y + beta.y * s.y;
        s.z = w.z + beta.z * s.z; s.w = w.w + beta.w * s.w;
        x.x += alpha.x * p.x; x.y += alpha.y * p.y;
        x.z += alpha.z * p.z; x.w += alpha.w * p.w;
        r.x -= alpha.x * s.x; r.y -= alpha.y * s.y;
        r.z -= alpha.z * s.z; r.w -= alpha.w * s.w;
        u = make_float4(mi * r.x, mi * r.y, mi * r.z, mi * r.w);
        gp = g; alp = alpha;
        if (i == NITERS - 1) break;

        st4(a.Ubuf + e, u);
        reduce_accum_16(make_float4(r.x * u.x, r.y * u.y, r.z * u.z, r.w * u.w),
                        a.dots + (2 * i + 2) * NS, sm);
        gbar(a.cnt, (++epoch) * nb);

        float4 q0 = ld4(a.Ubuf + n0), q1 = ld4(a.Ubuf + n1),
               q2 = ld4(a.Ubuf + n2), q3 = ld4(a.Ubuf + n3),
               q4 = ld4(a.Ubuf + n4), q5 = ld4(a.Ubuf + n5);
        w.x = ad * u.x + tt * (w0 * q0.x + w1 * q1.x + w2 * q2.x +
                               w3 * q3.x + w4 * q4.x + w5 * q5.x);
        w.y = ad * u.y + tt * (w0 * q0.y + w1 * q1.y + w2 * q2.y +
                               w3 * q3.y + w4 * q4.y + w5 * q5.y);
        w.z = ad * u.z + tt * (w0 * q0.z + w1 * q1.z + w2 * q2.z +
                               w3 * q3.z + w4 * q4.z + w5 * q5.z);
        w.w = ad * u.w + tt * (w0 * q0.w + w1 * q1.w + w2 * q2.w +
                               w3 * q3.w + w4 * q4.w + w5 * q5.w);
        reduce_accum_16(make_float4(w.x * u.x, w.y * u.y, w.z * u.z, w.w * u.w),
                        a.dots + (2 * i + 3) * NS, sm);
        gbar(a.cnt, (++epoch) * nb);
    }

    // ---- write U, S
    st4(a.U + e, x);
    {
        float u0 = x.x, u1 = x.y, u2 = x.z, u3 = x.w;
        u0 = isnan(u0) ? 1e-9f : (isinf(u0) ? (u0 > 0 ? 1.0f : 0.0f) : u0);
        u1 = isnan(u1) ? 1e-9f : (isinf(u1) ? (u1 > 0 ? 1.0f : 0.0f) : u1);
        u2 = isnan(u2) ? 1e-9f : (isinf(u2) ? (u2 > 0 ? 1.0f : 0.0f) : u2);
        u3 = isnan(u3) ? 1e-9f : (isinf(u3) ? (u3 > 0 ? 1.0f : 0.0f) : u3);
        float4 s4;
        s4.x = -logf(fmaxf(u0, 1e-9f));
        s4.y = -logf(fmaxf(u1, 1e-9f));
        s4.z = -logf(fmaxf(u2, 1e-9f));
        s4.w = -logf(fmaxf(u3, 1e-9f));
        st4(a.S + e, s4);
    }
    gbar(a.cnt, (++epoch) * nb);  // U visible grid-wide

    // ---- epilogue: Xdir (validated round 2)
    const int nchunks = a.nF * 4;
    const int gsz = gridDim.x * CG_TPB;
    const int t0 = blockIdx.x * CG_TPB + threadIdx.x;
    for (int idx = t0; idx < nchunks; idx += gsz) {
        int f = idx >> 2;
        int sb2 = (idx & 3) * 4;
        int i0 = a.F[3 * f + 0], i1 = a.F[3 * f + 1], i2 = a.F[3 * f + 2];
        float4 uI = ld4(a.U + i0 * NS + sb2);
        float4 uJ = ld4(a.U + i1 * NS + sb2);
        float4 uK = ld4(a.U + i2 * NS + sb2);
        float gIx = a.gI[3 * f], gIy = a.gI[3 * f + 1], gIz = a.gI[3 * f + 2];
        float gJx = a.gJ[3 * f], gJy = a.gJ[3 * f + 1], gJz = a.gJ[3 * f + 2];
        float gKx = a.gK[3 * f], gKy = a.gK[3 * f + 1], gKz = a.gK[3 * f + 2];
        float4 gx, gy, gz;
        gx.x = uI.x * gIx + uJ.x * gJx + uK.x * gKx;
        gx.y = uI.y * gIx + uJ.y * gJx + uK.y * gKx;
        gx.z = uI.z * gIx + uJ.z * gJx + uK.z * gKx;
        gx.w = uI.w * gIx + uJ.w * gJx + uK.w * gKx;
        gy.x = uI.x * gIy + uJ.x * gJy + uK.x * gKy;
        gy.y = uI.y * gIy + uJ.y * gJy + uK.y * gKy;
        gy.z = uI.z * gIy + uJ.z * gJy + uK.z * gKy;
        gy.w = uI.w * gIy + uJ.w * gJy + uK.w * gKy;
        gz.x = uI.x * gIz + uJ.x * gJz + uK.x * gKz;
        gz.y = uI.y * gIz + uJ.y * gJz + uK.y * gKz;
        gz.z = uI.z * gIz + uJ.z * gJz + uK.z * gKz;
        gz.w = uI.w * gIz + uJ.w * gJz + uK.w * gKz;
        float4 iv;
        iv.x = -1.0f / fmaxf(sqrtf(gx.x * gx.x + gy.x * gy.x + gz.x * gz.x), 1e-12f);
        iv.y = -1.0f / fmaxf(sqrtf(gx.y * gx.y + gy.y * gy.y + gz.y * gz.y), 1e-12f);
        iv.z = -1.0f / fmaxf(sqrtf(gx.z * gx.z + gy.z * gy.z + gz.z * gz.z), 1e-12f);
        iv.w = -1.0f / fmaxf(sqrtf(gx.w * gx.w + gy.w * gy.w + gz.w * gz.w), 1e-12f);
        float* o = a.Xdir + (size_t)f * 48 + sb2 * 3;
        st4(o + 0, make_float4(gx.x * iv.x, gy.x * iv.x, gz.x * iv.x, gx.y * iv.y));
        st4(o + 4, make_float4(gy.y * iv.y, gz.y * iv.y, gx.z * iv.z, gy.z * iv.z));
        st4(o + 8, make_float4(gz.z * iv.z, gx.w * iv.w, gy.w * iv.w, gz.w * iv.w));
    }
}

extern "C" void kernel_launch(void* const* d_in, const int* in_sizes, int n_in,
                              void* d_out, int out_size, void* d_ws, size_t ws_size,
                              hipStream_t stream) {
    const int*   F      = (const int*)d_in[0];
    const int*   row    = (const int*)d_in[1];
    const int*   col    = (const int*)d_in[2];
    const float* val    = (const float*)d_in[3];
    const float* M_diag = (const float*)d_in[4];
    const float* gI     = (const float*)d_in[5];
    const float* gJ     = (const float*)d_in[6];
    const float* gK     = (const float*)d_in[7];
    const float* B      = (const float*)d_in[8];
    const float* tptr   = (const float*)d_in[9];

    const int nF   = in_sizes[0] / 3;        // 130050
    const int nnz  = in_sizes[1];            // 1560600
    const int nV   = in_sizes[4];            // 65536
    const int ntot = nV * NS;                // 1048576
    const int stride = (int)(sqrt((double)nV) + 0.5);  // 256

    float* out = (float*)d_out;
    float* U = out;
    float* Xdir = out + (size_t)ntot;
    float* S = out + (size_t)ntot + (size_t)nF * 48;

    // Scratch inside the Xdir region (dead until epilogue overwrites it):
    float* Ubuf  = Xdir;                           // ntot
    float* W     = Xdir + (size_t)ntot;            // 6*nV
    float* diagL = W + (size_t)6 * nV;             // nV
    float* Adiag = diagL + nV;                     // nV
    float* Minv  = Adiag + nV;                     // nV
    float* dots  = Minv + nV;                      // 2*NITERS*16
    int*   cnt   = (int*)(dots + 2 * NITERS * NS);

    hipMemsetAsync(W, 0, (size_t)7 * nV * sizeof(float), stream);
    hipMemsetAsync(dots, 0, ((size_t)2 * NITERS * NS + 16) * sizeof(float),
                   stream);

    k_scatter<<<(nnz + TPB - 1) / TPB, TPB, 0, stream>>>(row, col, val, W, diagL,
                                                         nnz, nV, stride);
    k_diag<<<(nV + TPB - 1) / TPB, TPB, 0, stream>>>(M_diag, diagL, tptr,
                                                     Adiag, Minv, nV);

    const int blocks = (nV * 4) / CG_TPB;   // 256
    CgArgs a;
    a.B = B; a.W = W; a.Adiag = Adiag; a.Minv = Minv; a.tptr = tptr;
    a.Ubuf = Ubuf; a.dots = dots; a.cnt = cnt;
    a.U = U; a.S = S; a.Xdir = Xdir;
    a.F = F; a.gI = gI; a.gJ = gJ; a.gK = gK;
    a.nV = nV; a.nF = nF; a.stride = stride; a.nblocks = blocks;

    void* args[] = { &a };
    hipLaunchCooperativeKernel((void*)k_cg, dim3(blocks), dim3(CG_TPB),
                               args, 0, stream);
}

// Round 5
// 749.967 us; speedup vs baseline: 4.9988x; 2.8685x over previous
//
#include <hip/hip_runtime.h>
#include <math.h>

#define NS 16
#define NITERS 40
#define TPB 256
#define CG_TPB 1024
#define NBLK 256
#define NLOC 32   // blocks per barrier group (NBLK/8)

typedef float f4 __attribute__((ext_vector_type(4)));

__device__ __forceinline__ f4 vmax4(f4 a, float b) {
    f4 r; r.x = fmaxf(a.x, b); r.y = fmaxf(a.y, b);
    r.z = fmaxf(a.z, b); r.w = fmaxf(a.w, b); return r;
}

// ---- coherent (sc0 sc1) accesses for cross-block data: bypass stale L1/L2 --
__device__ __forceinline__ void st4_coh(float* base, int boff, f4 v) {
    asm volatile("global_store_dwordx4 %0, %1, %2 sc0 sc1"
                 :: "v"(boff), "v"(v), "s"(base) : "memory");
}
// 6-point stencil gather, batched (one waitcnt)
__device__ __forceinline__ void gather6(const float* base, int o0, int o1,
                                        int o2, int o3, int o4, int o5,
                                        f4& q0, f4& q1, f4& q2,
                                        f4& q3, f4& q4, f4& q5) {
    asm volatile(
        "global_load_dwordx4 %0, %6, %12 sc0 sc1\n\t"
        "global_load_dwordx4 %1, %7, %12 sc0 sc1\n\t"
        "global_load_dwordx4 %2, %8, %12 sc0 sc1\n\t"
        "global_load_dwordx4 %3, %9, %12 sc0 sc1\n\t"
        "global_load_dwordx4 %4, %10, %12 sc0 sc1\n\t"
        "global_load_dwordx4 %5, %11, %12 sc0 sc1\n\t"
        "s_waitcnt vmcnt(0)"
        : "=&v"(q0), "=&v"(q1), "=&v"(q2), "=&v"(q3), "=&v"(q4), "=&v"(q5)
        : "v"(o0), "v"(o1), "v"(o2), "v"(o3), "v"(o4), "v"(o5), "s"(base)
        : "memory");
}
// Sum this thread's 4-seed dot slice across the 8 group partial slots.
__device__ __forceinline__ f4 read_dot8(const float* base, int sboff) {
    f4 a0, a1, a2, a3, a4, a5, a6, a7;
    asm volatile(
        "global_load_dwordx4 %0, %8, %9 sc0 sc1\n\t"
        "global_load_dwordx4 %1, %8, %9 offset:64 sc0 sc1\n\t"
        "global_load_dwordx4 %2, %8, %9 offset:128 sc0 sc1\n\t"
        "global_load_dwordx4 %3, %8, %9 offset:192 sc0 sc1\n\t"
        "global_load_dwordx4 %4, %8, %9 offset:256 sc0 sc1\n\t"
        "global_load_dwordx4 %5, %8, %9 offset:320 sc0 sc1\n\t"
        "global_load_dwordx4 %6, %8, %9 offset:384 sc0 sc1\n\t"
        "global_load_dwordx4 %7, %8, %9 offset:448 sc0 sc1\n\t"
        "s_waitcnt vmcnt(0)"
        : "=&v"(a0), "=&v"(a1), "=&v"(a2), "=&v"(a3),
          "=&v"(a4), "=&v"(a5), "=&v"(a6), "=&v"(a7)
        : "v"(sboff), "s"(base)
        : "memory");
    return ((a0 + a1) + (a2 + a3)) + ((a4 + a5) + (a6 + a7));
}
// 3 U-loads for the epilogue, batched
__device__ __forceinline__ void gather3(const float* base, int oI, int oJ,
                                        int oK, f4& uI, f4& uJ, f4& uK) {
    asm volatile(
        "global_load_dwordx4 %0, %3, %6 sc0 sc1\n\t"
        "global_load_dwordx4 %1, %4, %6 sc0 sc1\n\t"
        "global_load_dwordx4 %2, %5, %6 sc0 sc1\n\t"
        "s_waitcnt vmcnt(0)"
        : "=&v"(uI), "=&v"(uJ), "=&v"(uK)
        : "v"(oI), "v"(oJ), "v"(oK), "s"(base)
        : "memory");
}

// ---- fence-free two-level grid barrier (coherence via sc0sc1 accesses) ----
__device__ __forceinline__ void gbar(int* cntL, int* cntG, int grp, int epoch) {
    asm volatile("s_waitcnt vmcnt(0)" ::: "memory");  // drain coherent stores
    __syncthreads();
    if (threadIdx.x == 0) {
        int old = __hip_atomic_fetch_add(&cntL[grp * 64], 1, __ATOMIC_RELAXED,
                                         __HIP_MEMORY_SCOPE_AGENT);
        if (old == epoch * NLOC - 1) {
            __hip_atomic_fetch_add(cntG, 1, __ATOMIC_RELAXED,
                                   __HIP_MEMORY_SCOPE_AGENT);
        }
        while (__hip_atomic_load(cntG, __ATOMIC_RELAXED,
                                 __HIP_MEMORY_SCOPE_AGENT) < epoch * 8) {
            __builtin_amdgcn_s_sleep(2);
        }
    }
    __syncthreads();
}

// Reduce per-thread f4 partials (seed classes (tid&3)*4..+3) -> 16 sums,
// atomicAdd into this group's 16-float slot of dst.
__device__ __forceinline__ void reduce_accum_16(f4 val, float* dst, f4* sm) {
#pragma unroll
    for (int off = 4; off < 64; off <<= 1) {
        val.x += __shfl_xor(val.x, off, 64);
        val.y += __shfl_xor(val.y, off, 64);
        val.z += __shfl_xor(val.z, off, 64);
        val.w += __shfl_xor(val.w, off, 64);
    }
    const int tid = threadIdx.x, lane = tid & 63, wave = tid >> 6;
    if (lane < 4) sm[wave * 4 + lane] = val;
    __syncthreads();
    if (tid < 4) {
        f4 acc = sm[tid];
#pragma unroll
        for (int w2 = 1; w2 < CG_TPB / 64; ++w2) acc += sm[w2 * 4 + tid];
        atomicAdd(&dst[tid * 4 + 0], acc.x);
        atomicAdd(&dst[tid * 4 + 1], acc.y);
        atomicAdd(&dst[tid * 4 + 2], acc.z);
        atomicAdd(&dst[tid * 4 + 3], acc.w);
    }
    __syncthreads();
}

// ---------------------------------------------------------------------------
// COO -> stencil scatter + diag (validated rounds 1-3, separate dispatches).
// ---------------------------------------------------------------------------
__global__ __launch_bounds__(TPB) void k_scatter(
    const int* __restrict__ row, const int* __restrict__ col,
    const float* __restrict__ val, float* __restrict__ W,
    float* __restrict__ diagL, int nnz, int nV, int stride) {
    int e = blockIdx.x * TPB + threadIdx.x;
    if (e >= nnz) return;
    int r = row[e], c = col[e];
    float v = val[e];
    if (r == c) { atomicAdd(&diagL[r], v); return; }
    int off = c - r;
    int slot;
    if      (off == -stride - 1) slot = 0;
    else if (off == -stride)     slot = 1;
    else if (off == -1)          slot = 2;
    else if (off == 1)           slot = 3;
    else if (off == stride)      slot = 4;
    else if (off == stride + 1)  slot = 5;
    else return;
    atomicAdd(&W[slot * nV + r], v);
}

__global__ __launch_bounds__(TPB) void k_diag(
    const float* __restrict__ M_diag, const float* __restrict__ diagL,
    const float* __restrict__ tptr, float* __restrict__ Adiag,
    float* __restrict__ Minv, int nV) {
    int v = blockIdx.x * TPB + threadIdx.x;
    if (v >= nV) return;
    float t = tptr[0];
    float a = M_diag[v] + t * diagL[v];
    Adiag[v] = a;
    Minv[v] = 1.0f / fmaxf(a, 1e-12f);
}

struct CgArgs {
    const float* B;
    const float* W;
    const float* Adiag;
    const float* Minv;
    const float* tptr;
    float* Ubuf;   // u-halo buffer (only cross-block CG vector)
    float* dots;   // slot j = dots + j*128: 8 groups x 16 floats
    int* cntL; int* cntG;
    float* U; float* S; float* Xdir;
    const int* F;
    const float* gI; const float* gJ; const float* gK;
    int nV; int nF; int stride;
};

// ---------------------------------------------------------------------------
// Chronopoulos-Gear PCG (round-3 numerics, VALIDATED: fresh matvec per iter).
// Thread t (XCD-banded) owns vertex v=t>>2, seeds sb..sb+3. x,r,p,s,w in regs.
// 2 fence-free barriers/iteration.
// ---------------------------------------------------------------------------
__global__ __launch_bounds__(CG_TPB, 4) void k_cg(CgArgs a) {
    __shared__ f4 sm[(CG_TPB / 64) * 4];
    const int nV = a.nV;
    const int grp = blockIdx.x & 7;
    const int ob = grp * NLOC + (blockIdx.x >> 3);
    const int t  = ob * CG_TPB + threadIdx.x;
    const int rt = blockIdx.x * CG_TPB + threadIdx.x;
    const int v  = t >> 2;
    const int sb = (t & 3) * 4;
    const int e  = t * 4;
    const int eb = e * 4;     // byte offset of this thread's f4
    const int sbb = sb * 4;   // byte offset into a 16-float slot

    const float tt = a.tptr[0];
    const float w0 = a.W[0 * nV + v], w1 = a.W[1 * nV + v];
    const float w2 = a.W[2 * nV + v], w3 = a.W[3 * nV + v];
    const float w4 = a.W[4 * nV + v], w5 = a.W[5 * nV + v];
    const float ad = a.Adiag[v];
    const float mi = a.Minv[v];
    const int st = a.stride;
    const int o0 = (max(0, min(v - st - 1, nV - 1)) * NS + sb) * 4;
    const int o1 = (max(0, min(v - st,     nV - 1)) * NS + sb) * 4;
    const int o2 = (max(0, min(v - 1,      nV - 1)) * NS + sb) * 4;
    const int o3 = (max(0, min(v + 1,      nV - 1)) * NS + sb) * 4;
    const int o4 = (max(0, min(v + st,     nV - 1)) * NS + sb) * 4;
    const int o5 = (max(0, min(v + st + 1, nV - 1)) * NS + sb) * 4;

    int epoch = 0;

    // ---- init: r=B, u=Minv*r, publish u, gamma0 -> slot 0
    f4 x = (f4)(0.0f), p = (f4)(0.0f), s = (f4)(0.0f);
    f4 r = *(const f4*)(a.B + e);
    f4 u = mi * r;
    st4_coh(a.Ubuf, eb, u);
    reduce_accum_16(r * u, a.dots + 0 * 128 + grp * 16, sm);
    gbar(a.cntL, a.cntG, grp, ++epoch);

    // ---- w0 = A u0 ; delta0 -> slot 1
    f4 q0, q1, q2, q3, q4, q5;
    gather6(a.Ubuf, o0, o1, o2, o3, o4, o5, q0, q1, q2, q3, q4, q5);
    f4 w = ad * u + tt * (w0 * q0 + w1 * q1 + w2 * q2 +
                          w3 * q3 + w4 * q4 + w5 * q5);
    reduce_accum_16(w * u, a.dots + 1 * 128 + grp * 16, sm);
    gbar(a.cntL, a.cntG, grp, ++epoch);

    f4 gp = (f4)(1.0f), alp = (f4)(1.0f);
    for (int i = 0; i < NITERS; ++i) {
        f4 g = read_dot8(a.dots + (2 * i) * 128, sbb);
        f4 d = read_dot8(a.dots + (2 * i + 1) * 128, sbb);
        f4 beta, alpha;
        if (i == 0) {
            beta = (f4)(0.0f);
            alpha = g / vmax4(d, 1e-30f);
        } else {
            beta = g / vmax4(gp, 1e-30f);
            alpha = g / vmax4(d - beta * g / alp, 1e-30f);
        }
        p = u + beta * p;
        s = w + beta * s;
        x += alpha * p;
        r -= alpha * s;
        u = mi * r;
        gp = g; alp = alpha;
        if (i == NITERS - 1) break;

        st4_coh(a.Ubuf, eb, u);   // safe: all gathers of old u done (barrier B)
        reduce_accum_16(r * u, a.dots + (2 * i + 2) * 128 + grp * 16, sm);
        gbar(a.cntL, a.cntG, grp, ++epoch);   // barrier A

        gather6(a.Ubuf, o0, o1, o2, o3, o4, o5, q0, q1, q2, q3, q4, q5);
        w = ad * u + tt * (w0 * q0 + w1 * q1 + w2 * q2 +
                           w3 * q3 + w4 * q4 + w5 * q5);
        reduce_accum_16(w * u, a.dots + (2 * i + 3) * 128 + grp * 16, sm);
        gbar(a.cntL, a.cntG, grp, ++epoch);   // barrier B
    }

    // ---- write U (coherent; re-read in epilogue) and S (plain)
    st4_coh(a.U, eb, x);
    {
        float uu[4] = {x.x, x.y, x.z, x.w};
        f4 s4;
#pragma unroll
        for (int k = 0; k < 4; ++k) {
            float c = uu[k];
            c = isnan(c) ? 1e-9f : (isinf(c) ? (c > 0 ? 1.0f : 0.0f) : c);
            uu[k] = -logf(fmaxf(c, 1e-9f));
        }
        s4.x = uu[0]; s4.y = uu[1]; s4.z = uu[2]; s4.w = uu[3];
        *(f4*)(a.S + e) = s4;
    }
    gbar(a.cntL, a.cntG, grp, ++epoch);   // U visible grid-wide

    // ---- epilogue: Xdir
    const int nchunks = a.nF * 4;
    for (int idx = rt; idx < nchunks; idx += NBLK * CG_TPB) {
        int f = idx >> 2;
        int sb2 = (idx & 3) * 4;
        int i0 = a.F[3 * f + 0], i1 = a.F[3 * f + 1], i2 = a.F[3 * f + 2];
        f4 uI, uJ, uK;
        gather3(a.U, (i0 * NS + sb2) * 4, (i1 * NS + sb2) * 4,
                (i2 * NS + sb2) * 4, uI, uJ, uK);
        float gIx = a.gI[3 * f], gIy = a.gI[3 * f + 1], gIz = a.gI[3 * f + 2];
        float gJx = a.gJ[3 * f], gJy = a.gJ[3 * f + 1], gJz = a.gJ[3 * f + 2];
        float gKx = a.gK[3 * f], gKy = a.gK[3 * f + 1], gKz = a.gK[3 * f + 2];
        f4 gx = uI * gIx + uJ * gJx + uK * gKx;
        f4 gy = uI * gIy + uJ * gJy + uK * gKy;
        f4 gz = uI * gIz + uJ * gJz + uK * gKz;
        f4 iv;
        iv.x = -1.0f / fmaxf(sqrtf(gx.x * gx.x + gy.x * gy.x + gz.x * gz.x), 1e-12f);
        iv.y = -1.0f / fmaxf(sqrtf(gx.y * gx.y + gy.y * gy.y + gz.y * gz.y), 1e-12f);
        iv.z = -1.0f / fmaxf(sqrtf(gx.z * gx.z + gy.z * gy.z + gz.z * gz.z), 1e-12f);
        iv.w = -1.0f / fmaxf(sqrtf(gx.w * gx.w + gy.w * gy.w + gz.w * gz.w), 1e-12f);
        float* o = a.Xdir + (size_t)f * 48 + sb2 * 3;
        *(f4*)(o + 0) = (f4){gx.x * iv.x, gy.x * iv.x, gz.x * iv.x, gx.y * iv.y};
        *(f4*)(o + 4) = (f4){gy.y * iv.y, gz.y * iv.y, gx.z * iv.z, gy.z * iv.z};
        *(f4*)(o + 8) = (f4){gz.z * iv.z, gx.w * iv.w, gy.w * iv.w, gz.w * iv.w};
    }
}

extern "C" void kernel_launch(void* const* d_in, const int* in_sizes, int n_in,
                              void* d_out, int out_size, void* d_ws, size_t ws_size,
                              hipStream_t stream) {
    const int*   F      = (const int*)d_in[0];
    const int*   row    = (const int*)d_in[1];
    const int*   col    = (const int*)d_in[2];
    const float* val    = (const float*)d_in[3];
    const float* M_diag = (const float*)d_in[4];
    const float* gI     = (const float*)d_in[5];
    const float* gJ     = (const float*)d_in[6];
    const float* gK     = (const float*)d_in[7];
    const float* B      = (const float*)d_in[8];
    const float* tptr   = (const float*)d_in[9];

    const int nF   = in_sizes[0] / 3;        // 130050
    const int nnz  = in_sizes[1];            // 1560600
    const int nV   = in_sizes[4];            // 65536
    const int ntot = nV * NS;                // 1048576
    const int stride = (int)(sqrt((double)nV) + 0.5);  // 256

    float* out = (float*)d_out;
    float* U = out;
    float* Xdir = out + (size_t)ntot;
    float* S = out + (size_t)ntot + (size_t)nF * 48;

    // Scratch inside Xdir region (dead until epilogue): ~1.65M floats < 6.24M
    float* Ubuf  = Xdir;                           // ntot
    float* W     = Xdir + (size_t)ntot;            // 6*nV
    float* diagL = W + (size_t)6 * nV;             // nV
    float* Adiag = diagL + nV;                     // nV
    float* Minv  = Adiag + nV;                     // nV
    float* dots  = Minv + nV;                      // 80 slots * 128 floats
    int*   cntL  = (int*)(dots + 80 * 128);        // 8 * 64 ints
    int*   cntG  = cntL + 8 * 64;

    hipMemsetAsync(W, 0, (size_t)7 * nV * sizeof(float), stream);
    hipMemsetAsync(dots, 0, (80 * 128 + 8 * 64 + 16) * sizeof(float), stream);

    k_scatter<<<(nnz + TPB - 1) / TPB, TPB, 0, stream>>>(row, col, val, W, diagL,
                                                         nnz, nV, stride);
    k_diag<<<(nV + TPB - 1) / TPB, TPB, 0, stream>>>(M_diag, diagL, tptr,
                                                     Adiag, Minv, nV);

    CgArgs a;
    a.B = B; a.W = W; a.Adiag = Adiag; a.Minv = Minv; a.tptr = tptr;
    a.Ubuf = Ubuf; a.dots = dots; a.cntL = cntL; a.cntG = cntG;
    a.U = U; a.S = S; a.Xdir = Xdir;
    a.F = F; a.gI = gI; a.gJ = gJ; a.gK = gK;
    a.nV = nV; a.nF = nF; a.stride = stride;

    void* args[] = { &a };
    hipLaunchCooperativeKernel((void*)k_cg, dim3(NBLK), dim3(CG_TPB),
                               args, 0, stream);
}

// Round 7
// 634.566 us; speedup vs baseline: 5.9079x; 1.1819x over previous
//
#include <hip/hip_runtime.h>
#include <math.h>

#define NS 16
#define NITERS 40
#define CG_TPB 1024
#define NBLK 256
#define NLOC 32   // blocks per barrier group (NBLK/8)

typedef float f4 __attribute__((ext_vector_type(4)));

__device__ __forceinline__ f4 vmax4(f4 a, float b) {
    f4 r; r.x = fmaxf(a.x, b); r.y = fmaxf(a.y, b);
    r.z = fmaxf(a.z, b); r.w = fmaxf(a.w, b); return r;
}

// ---- coherent (sc0 sc1) accesses for cross-block data (validated r5) ----
__device__ __forceinline__ void st4_coh(float* base, int boff, f4 v) {
    asm volatile("global_store_dwordx4 %0, %1, %2 sc0 sc1"
                 :: "v"(boff), "v"(v), "s"(base) : "memory");
}
__device__ __forceinline__ float ldf_coh(const float* base, int boff) {
    float r;
    asm volatile("global_load_dword %0, %1, %2 sc0 sc1\n\t"
                 "s_waitcnt vmcnt(0)"
                 : "=v"(r) : "v"(boff), "s"(base) : "memory");
    return r;
}
// Issue 4 cross-row gathers WITHOUT waiting (overlap with LDS work).
__device__ __forceinline__ void issue4(const float* base, int o0, int o1,
                                       int o4, int o5, f4& q0, f4& q1,
                                       f4& q4, f4& q5) {
    asm volatile(
        "global_load_dwordx4 %0, %4, %8 sc0 sc1\n\t"
        "global_load_dwordx4 %1, %5, %8 sc0 sc1\n\t"
        "global_load_dwordx4 %2, %6, %8 sc0 sc1\n\t"
        "global_load_dwordx4 %3, %7, %8 sc0 sc1"
        : "=&v"(q0), "=&v"(q1), "=&v"(q4), "=&v"(q5)
        : "v"(o0), "v"(o1), "v"(o4), "v"(o5), "s"(base)
        : "memory");
}
__device__ __forceinline__ void wait4(f4& q0, f4& q1, f4& q4, f4& q5) {
    asm volatile("s_waitcnt vmcnt(0)"
                 : "+v"(q0), "+v"(q1), "+v"(q4), "+v"(q5) :: "memory");
}
__device__ __forceinline__ void gatherW6(const float* base, int o0, int o1,
                                         int o2, int o3, int o4, int o5,
                                         float& w0, float& w1, float& w2,
                                         float& w3, float& w4, float& w5) {
    asm volatile(
        "global_load_dword %0, %6, %12 sc0 sc1\n\t"
        "global_load_dword %1, %7, %12 sc0 sc1\n\t"
        "global_load_dword %2, %8, %12 sc0 sc1\n\t"
        "global_load_dword %3, %9, %12 sc0 sc1\n\t"
        "global_load_dword %4, %10, %12 sc0 sc1\n\t"
        "global_load_dword %5, %11, %12 sc0 sc1\n\t"
        "s_waitcnt vmcnt(0)"
        : "=&v"(w0), "=&v"(w1), "=&v"(w2), "=&v"(w3), "=&v"(w4), "=&v"(w5)
        : "v"(o0), "v"(o1), "v"(o2), "v"(o3), "v"(o4), "v"(o5), "s"(base)
        : "memory");
}
// Read BOTH dot slots (gamma at +0, delta at +512B), 8 group-partials each.
__device__ __forceinline__ void read_dot2x8(const float* base, int sboff,
                                            f4& gs, f4& ds) {
    f4 a0,a1,a2,a3,a4,a5,a6,a7, b0,b1,b2,b3,b4,b5,b6,b7;
    asm volatile(
        "global_load_dwordx4 %0, %16, %17 sc0 sc1\n\t"
        "global_load_dwordx4 %1, %16, %17 offset:64 sc0 sc1\n\t"
        "global_load_dwordx4 %2, %16, %17 offset:128 sc0 sc1\n\t"
        "global_load_dwordx4 %3, %16, %17 offset:192 sc0 sc1\n\t"
        "global_load_dwordx4 %4, %16, %17 offset:256 sc0 sc1\n\t"
        "global_load_dwordx4 %5, %16, %17 offset:320 sc0 sc1\n\t"
        "global_load_dwordx4 %6, %16, %17 offset:384 sc0 sc1\n\t"
        "global_load_dwordx4 %7, %16, %17 offset:448 sc0 sc1\n\t"
        "global_load_dwordx4 %8, %16, %17 offset:512 sc0 sc1\n\t"
        "global_load_dwordx4 %9, %16, %17 offset:576 sc0 sc1\n\t"
        "global_load_dwordx4 %10, %16, %17 offset:640 sc0 sc1\n\t"
        "global_load_dwordx4 %11, %16, %17 offset:704 sc0 sc1\n\t"
        "global_load_dwordx4 %12, %16, %17 offset:768 sc0 sc1\n\t"
        "global_load_dwordx4 %13, %16, %17 offset:832 sc0 sc1\n\t"
        "global_load_dwordx4 %14, %16, %17 offset:896 sc0 sc1\n\t"
        "global_load_dwordx4 %15, %16, %17 offset:960 sc0 sc1\n\t"
        "s_waitcnt vmcnt(0)"
        : "=&v"(a0), "=&v"(a1), "=&v"(a2), "=&v"(a3),
          "=&v"(a4), "=&v"(a5), "=&v"(a6), "=&v"(a7),
          "=&v"(b0), "=&v"(b1), "=&v"(b2), "=&v"(b3),
          "=&v"(b4), "=&v"(b5), "=&v"(b6), "=&v"(b7)
        : "v"(sboff), "s"(base)
        : "memory");
    gs = ((a0 + a1) + (a2 + a3)) + ((a4 + a5) + (a6 + a7));
    ds = ((b0 + b1) + (b2 + b3)) + ((b4 + b5) + (b6 + b7));
}
__device__ __forceinline__ void gather3(const float* base, int oI, int oJ,
                                        int oK, f4& uI, f4& uJ, f4& uK) {
    asm volatile(
        "global_load_dwordx4 %0, %3, %6 sc0 sc1\n\t"
        "global_load_dwordx4 %1, %4, %6 sc0 sc1\n\t"
        "global_load_dwordx4 %2, %5, %6 sc0 sc1\n\t"
        "s_waitcnt vmcnt(0)"
        : "=&v"(uI), "=&v"(uJ), "=&v"(uK)
        : "v"(oI), "v"(oJ), "v"(oK), "s"(base)
        : "memory");
}

// ---- fence-free two-level grid barrier (validated r5) ----
__device__ __forceinline__ void gbar(int* cntL, int* cntG, int grp, int epoch) {
    asm volatile("s_waitcnt vmcnt(0)" ::: "memory");
    __syncthreads();
    if (threadIdx.x == 0) {
        int old = __hip_atomic_fetch_add(&cntL[grp * 64], 1, __ATOMIC_RELAXED,
                                         __HIP_MEMORY_SCOPE_AGENT);
        if (old == epoch * NLOC - 1) {
            __hip_atomic_fetch_add(cntG, 1, __ATOMIC_RELAXED,
                                   __HIP_MEMORY_SCOPE_AGENT);
        }
        while (__hip_atomic_load(cntG, __ATOMIC_RELAXED,
                                 __HIP_MEMORY_SCOPE_AGENT) < epoch * 8) {
            __builtin_amdgcn_s_sleep(2);
        }
    }
    __syncthreads();
}

// Dual f4 partials (gamma, delta) in one LDS pass -> two 16-float slots.
__device__ __forceinline__ void reduce_accum_2x16(f4 va, f4 vb, float* dA,
                                                  float* dB, f4* sm) {
#pragma unroll
    for (int off = 4; off < 64; off <<= 1) {
        va.x += __shfl_xor(va.x, off, 64);
        va.y += __shfl_xor(va.y, off, 64);
        va.z += __shfl_xor(va.z, off, 64);
        va.w += __shfl_xor(va.w, off, 64);
        vb.x += __shfl_xor(vb.x, off, 64);
        vb.y += __shfl_xor(vb.y, off, 64);
        vb.z += __shfl_xor(vb.z, off, 64);
        vb.w += __shfl_xor(vb.w, off, 64);
    }
    const int tid = threadIdx.x, lane = tid & 63, wave = tid >> 6;
    if (lane < 4) { sm[wave * 8 + lane] = va; sm[wave * 8 + 4 + lane] = vb; }
    __syncthreads();
    if (tid < 8) {
        const int c = tid & 3;
        const int half = (tid >> 2) * 4;
        f4 acc = sm[half + c];
#pragma unroll
        for (int w2 = 1; w2 < CG_TPB / 64; ++w2) acc += sm[w2 * 8 + half + c];
        float* dst = (tid < 4) ? dA : dB;
        atomicAdd(&dst[c * 4 + 0], acc.x);
        atomicAdd(&dst[c * 4 + 1], acc.y);
        atomicAdd(&dst[c * 4 + 2], acc.z);
        atomicAdd(&dst[c * 4 + 3], acc.w);
    }
    __syncthreads();
}

struct CgArgs {
    const int* F; const int* row; const int* col; const float* val;
    const float* M_diag; const float* gI; const float* gJ; const float* gK;
    const float* B; const float* tptr;
    float* Ubuf;                // u-halo (single buffer)
    float* W;                   // 6*nV, diagL = W + 6*nV
    float* dots;                // in d_ws: slot j = dots + j*128
    int* flags; int* cntL; int* cntG;   // in d_ws
    float* U; float* S; float* Xdir;
    int nV; int nF; int nnz; int stride;
};

// ---------------------------------------------------------------------------
// One cooperative kernel: scatter + diag + CG (round-5-validated numerics,
// Chronopoulos-Gear, fresh matvec per iter) + S + Xdir.
// Block b owns grid row ob (XCD-banded). u-publish syncs only with rows ob±1
// via per-row flags; one global barrier per iteration for the dot products.
// ---------------------------------------------------------------------------
__global__ __launch_bounds__(CG_TPB, 4) void k_cg(CgArgs a) {
    __shared__ f4 sm[(CG_TPB / 64) * 8];
    __shared__ f4 lds_u[CG_TPB];
    const int nV = a.nV;
    const int grp = blockIdx.x & 7;
    const int ob = grp * NLOC + (blockIdx.x >> 3);   // owned row
    const int tid = threadIdx.x;
    const int t  = ob * CG_TPB + tid;
    const int rt = blockIdx.x * CG_TPB + tid;
    const int v  = t >> 2;
    const int sb = (t & 3) * 4;
    const int e  = t * 4;
    const int eb = e * 4;
    const int sbb = sb * 4;
    const int obm1 = max(ob - 1, 0);
    const int obp1 = min(ob + 1, NBLK - 1);
    float* diagL = a.W + 6 * nV;
    int epoch = 0;

    // ---- phase 0: zero W+diagL via coherent stores
    const int nz4 = (7 * nV) / 4;
    if (rt < nz4) st4_coh(a.W, rt * 16, (f4)(0.0f));
    gbar(a.cntL, a.cntG, grp, ++epoch);

    // ---- phase 1: COO -> stencil scatter (device-scope atomics at LLC)
    {
        const int st = a.stride, nnz = a.nnz;
        for (int ei = rt; ei < nnz; ei += NBLK * CG_TPB) {
            int rr = a.row[ei], cc = a.col[ei];
            float vv = a.val[ei];
            if (rr == cc) { atomicAdd(&diagL[rr], vv); continue; }
            int off = cc - rr;
            int slot;
            if      (off == -st - 1) slot = 0;
            else if (off == -st)     slot = 1;
            else if (off == -1)      slot = 2;
            else if (off == 1)       slot = 3;
            else if (off == st)      slot = 4;
            else if (off == st + 1)  slot = 5;
            else continue;
            atomicAdd(&a.W[slot * nV + rr], vv);
        }
    }
    gbar(a.cntL, a.cntG, grp, ++epoch);

    // ---- per-vertex constants
    const float tt = a.tptr[0];
    float w0, w1, w2, w3, w4, w5;
    gatherW6(a.W, v * 4, (nV + v) * 4, (2 * nV + v) * 4, (3 * nV + v) * 4,
             (4 * nV + v) * 4, (5 * nV + v) * 4, w0, w1, w2, w3, w4, w5);
    const float ad = a.M_diag[v] + tt * ldf_coh(diagL, v * 4);
    const float mi = 1.0f / fmaxf(ad, 1e-12f);
    const int st = a.stride;
    const int o0 = (max(0, min(v - st - 1, nV - 1)) * NS + sb) * 4;
    const int o1 = (max(0, min(v - st,     nV - 1)) * NS + sb) * 4;
    const int o4 = (max(0, min(v + st,     nV - 1)) * NS + sb) * 4;
    const int o5 = (max(0, min(v + st + 1, nV - 1)) * NS + sb) * 4;
    const int lm = max(tid - 4, 0);           // v-1 (in-block; W=0 at row edge)
    const int lp = min(tid + 4, CG_TPB - 1);  // v+1

    // ================= publish+wait+matvec macro-block =================
    //   publishes u, waits rows ob±1 at version `it`, computes w = A u
#define PUBLISH_WAIT_MATVEC(IT, WOUT)                                         \
    {                                                                         \
        st4_coh(a.Ubuf, eb, u);                                               \
        lds_u[tid] = u;                                                       \
        asm volatile("s_waitcnt vmcnt(0)" ::: "memory");                      \
        __syncthreads();                                                      \
        if (tid == 0) {                                                       \
            __hip_atomic_store(&a.flags[ob * 16], (IT), __ATOMIC_RELAXED,     \
                               __HIP_MEMORY_SCOPE_AGENT);                     \
            while (__hip_atomic_load(&a.flags[obm1 * 16], __ATOMIC_RELAXED,   \
                                     __HIP_MEMORY_SCOPE_AGENT) < (IT))        \
                __builtin_amdgcn_s_sleep(1);                                  \
        } else if (tid == 64) {                                               \
            while (__hip_atomic_load(&a.flags[obp1 * 16], __ATOMIC_RELAXED,   \
                                     __HIP_MEMORY_SCOPE_AGENT) < (IT))        \
                __builtin_amdgcn_s_sleep(1);                                  \
        }                                                                     \
        __syncthreads();                                                      \
        f4 q0, q1, q4, q5;                                                    \
        issue4(a.Ubuf, o0, o1, o4, o5, q0, q1, q4, q5);                       \
        f4 q2 = lds_u[lm];                                                    \
        f4 q3 = lds_u[lp];                                                    \
        WOUT = ad * u + tt * (w2 * q2 + w3 * q3);                             \
        wait4(q0, q1, q4, q5);                                                \
        WOUT += tt * (w0 * q0 + w1 * q1 + w4 * q4 + w5 * q5);                 \
    }

    // ---- init: r0=B, u0=Minv r0; publish; w0=A u0; gamma0,delta0 -> slots 0,1
    f4 r = *(const f4*)(a.B + e);
    f4 u = mi * r;
    f4 w;
    PUBLISH_WAIT_MATVEC(1, w);
    reduce_accum_2x16(r * u, w * u, a.dots + 0 * 128 + grp * 16,
                      a.dots + 1 * 128 + grp * 16, sm);
    gbar(a.cntL, a.cntG, grp, ++epoch);

    // ---- main loop (round-5 numerics): 1 global barrier per iteration
    f4 x = (f4)(0.0f), p = (f4)(0.0f), s = (f4)(0.0f);
    f4 gp = (f4)(1.0f), alp = (f4)(1.0f);
    for (int i = 0; i < NITERS; ++i) {
        f4 g, d;
        read_dot2x8(a.dots + (2 * i) * 128, sbb, g, d);
        f4 beta, alpha;
        if (i == 0) {
            beta = (f4)(0.0f);
            alpha = g / vmax4(d, 1e-30f);
        } else {
            beta = g / vmax4(gp, 1e-30f);
            alpha = g / vmax4(d - beta * g / alp, 1e-30f);
        }
        p = u + beta * p;
        s = w + beta * s;
        x += alpha * p;
        r -= alpha * s;
        u = mi * r;
        gp = g; alp = alpha;
        if (i == NITERS - 1) break;

        PUBLISH_WAIT_MATVEC(i + 2, w);
        reduce_accum_2x16(r * u, w * u,
                          a.dots + (2 * i + 2) * 128 + grp * 16,
                          a.dots + (2 * i + 3) * 128 + grp * 16, sm);
        gbar(a.cntL, a.cntG, grp, ++epoch);
    }

    // ---- write U (coherent; re-read in epilogue) and S
    st4_coh(a.U, eb, x);
    {
        float uu[4] = {x.x, x.y, x.z, x.w};
        f4 s4;
#pragma unroll
        for (int k = 0; k < 4; ++k) {
            float c = uu[k];
            c = isnan(c) ? 1e-9f : (isinf(c) ? (c > 0 ? 1.0f : 0.0f) : c);
            uu[k] = -logf(fmaxf(c, 1e-9f));
        }
        s4.x = uu[0]; s4.y = uu[1]; s4.z = uu[2]; s4.w = uu[3];
        *(f4*)(a.S + e) = s4;
    }
    gbar(a.cntL, a.cntG, grp, ++epoch);   // U visible grid-wide

    // ---- epilogue: Xdir (safe: counters/dots/flags live in d_ws, not here)
    const int nchunks = a.nF * 4;
    for (int idx = rt; idx < nchunks; idx += NBLK * CG_TPB) {
        int f = idx >> 2;
        int sb2 = (idx & 3) * 4;
        int i0 = a.F[3 * f + 0], i1 = a.F[3 * f + 1], i2 = a.F[3 * f + 2];
        f4 uI, uJ, uK;
        gather3(a.U, (i0 * NS + sb2) * 4, (i1 * NS + sb2) * 4,
                (i2 * NS + sb2) * 4, uI, uJ, uK);
        float gIx = a.gI[3 * f], gIy = a.gI[3 * f + 1], gIz = a.gI[3 * f + 2];
        float gJx = a.gJ[3 * f], gJy = a.gJ[3 * f + 1], gJz = a.gJ[3 * f + 2];
        float gKx = a.gK[3 * f], gKy = a.gK[3 * f + 1], gKz = a.gK[3 * f + 2];
        f4 gx = uI * gIx + uJ * gJx + uK * gKx;
        f4 gy = uI * gIy + uJ * gJy + uK * gKy;
        f4 gz = uI * gIz + uJ * gJz + uK * gKz;
        f4 iv;
        iv.x = -1.0f / fmaxf(sqrtf(gx.x * gx.x + gy.x * gy.x + gz.x * gz.x), 1e-12f);
        iv.y = -1.0f / fmaxf(sqrtf(gx.y * gx.y + gy.y * gy.y + gz.y * gz.y), 1e-12f);
        iv.z = -1.0f / fmaxf(sqrtf(gx.z * gx.z + gy.z * gy.z + gz.z * gz.z), 1e-12f);
        iv.w = -1.0f / fmaxf(sqrtf(gx.w * gx.w + gy.w * gy.w + gz.w * gz.w), 1e-12f);
        float* o = a.Xdir + (size_t)f * 48 + sb2 * 3;
        *(f4*)(o + 0) = (f4){gx.x * iv.x, gy.x * iv.x, gz.x * iv.x, gx.y * iv.y};
        *(f4*)(o + 4) = (f4){gy.y * iv.y, gz.y * iv.y, gx.z * iv.z, gy.z * iv.z};
        *(f4*)(o + 8) = (f4){gz.z * iv.z, gx.w * iv.w, gy.w * iv.w, gz.w * iv.w};
    }
#undef PUBLISH_WAIT_MATVEC
}

extern "C" void kernel_launch(void* const* d_in, const int* in_sizes, int n_in,
                              void* d_out, int out_size, void* d_ws, size_t ws_size,
                              hipStream_t stream) {
    const int nF   = in_sizes[0] / 3;        // 130050
    const int nnz  = in_sizes[1];            // 1560600
    const int nV   = in_sizes[4];            // 65536
    const int ntot = nV * NS;                // 1048576
    const int stride = (int)(sqrt((double)nV) + 0.5);  // 256

    float* out = (float*)d_out;
    float* U = out;
    float* Xdir = out + (size_t)ntot;
    float* S = out + (size_t)ntot + (size_t)nF * 48;

    // Large scratch (dead before epilogue overwrites it) inside Xdir region:
    float* Ubuf = Xdir;                            // ntot
    float* W    = Xdir + (size_t)ntot;             // 6*nV + nV (diagL)

    // Sync/reduction state in d_ws — must SURVIVE the epilogue (rounds 5/6
    // kept it in Xdir: racy against epilogue stores clobbering counters).
    float* dots  = (float*)d_ws;                   // 82 slots * 128 floats
    int*   flags = (int*)(dots + 82 * 128);        // 256 rows * 16 ints
    int*   cntL  = flags + NBLK * 16;              // 8 * 64
    int*   cntG  = cntL + 8 * 64;                  // 16

    hipMemsetAsync(d_ws, 0,
                   (82 * 128 + NBLK * 16 + 8 * 64 + 16) * sizeof(float),
                   stream);

    CgArgs a;
    a.F = (const int*)d_in[0];
    a.row = (const int*)d_in[1];
    a.col = (const int*)d_in[2];
    a.val = (const float*)d_in[3];
    a.M_diag = (const float*)d_in[4];
    a.gI = (const float*)d_in[5];
    a.gJ = (const float*)d_in[6];
    a.gK = (const float*)d_in[7];
    a.B = (const float*)d_in[8];
    a.tptr = (const float*)d_in[9];
    a.Ubuf = Ubuf; a.W = W;
    a.dots = dots; a.flags = flags; a.cntL = cntL; a.cntG = cntG;
    a.U = U; a.S = S; a.Xdir = Xdir;
    a.nV = nV; a.nF = nF; a.nnz = nnz; a.stride = stride;

    void* args[] = { &a };
    hipLaunchCooperativeKernel((void*)k_cg, dim3(NBLK), dim3(CG_TPB),
                               args, 0, stream);
}